// Round 11
// baseline (297.637 us; speedup 1.0000x reference)
//
#include <hip/hip_runtime.h>
#include <hip/hip_bf16.h>

// HierarchicalMambaBlock: B=2,T=1024,DIM=512 -> D_INNER=1024, DT_RANK=64, D_STATE=16
// All tensors f32. GEMMs on MFMA via ON-THE-FLY split precision:
// stage f32 tiles into LDS as hi/lo bf16; acc += Ah*Bh + Al*Bh + Ah*Bl (~f32 accurate).
#define BATCH   2
#define SEQ     1024
#define DIMSZ   512
#define DINNER  1024
#define DTRANK  64
#define DSTATE  16
#define CHUNK   16

typedef __hip_bfloat16 bf16;
typedef __attribute__((ext_vector_type(8))) short s8v;   // 8 bf16 MFMA frag
typedef __attribute__((ext_vector_type(4))) float f4v;   // 4 f32 acc

__device__ __forceinline__ float sigmoidf_(float x) { return 1.f / (1.f + __expf(-x)); }
__device__ __forceinline__ float siluf_(float x) { return x * sigmoidf_(x); }
__device__ __forceinline__ void split2(float v, bf16& hi, bf16& lo) {
    hi = __float2bfloat16(v);
    lo = __float2bfloat16(v - __bfloat162float(hi));
}
__device__ __forceinline__ void split_store4(const float4 v,
                                             bf16* __restrict__ ph,
                                             bf16* __restrict__ pl) {
    union { bf16 b[4]; uint2 u; } H, L;
    split2(v.x, H.b[0], L.b[0]); split2(v.y, H.b[1], L.b[1]);
    split2(v.z, H.b[2], L.b[2]); split2(v.w, H.b[3], L.b[3]);
    *reinterpret_cast<uint2*>(ph) = H.u;
    *reinterpret_cast<uint2*>(pl) = L.u;
}

// ---------------------------------------------------------------------------
// MFMA GEMM, 64x64 tile, BK=64 f32, 4 waves (each 32x32 of 16x16x32 frags),
// register prefetch of next K-tile. A,W f32; split to hi/lo at LDS stage.
// ACT: 0 none, 1 silu, 2 sigmoid, 3 bias+softplus
// DT_MODE: stacked dtproj (M=3584): per-block W/bias select by scale
// CTX_A:   A[m,k] = (y0[m,k] + y1[up(m),k] + y2[up(m),k]) / 3   (cg1 fusion)
// GATE3:   v = softmax_fused(y0,y1,y2,sw)[gm,gn] * v * silu(xz gate)  (cg2 fusion)
// Requires: M,N multiples of 64, K multiple of 64, lda%4==0.
// ---------------------------------------------------------------------------
template <int ACT, bool ADD_RES, bool DT_MODE, bool CTX_A, bool GATE3>
__global__ __launch_bounds__(256) void mgemm_kernel(
    const float* __restrict__ A, int lda, int K,
    const float* __restrict__ W,            // ldw = K
    const float* __restrict__ bias,
    const float* __restrict__ res,          // residual (ADD_RES)
    const float* __restrict__ gxz,          // xz (GATE3)
    const float* __restrict__ yy0,          // CTX_A / GATE3
    const float* __restrict__ yy1,
    const float* __restrict__ yy2,
    const float* __restrict__ swp,          // GATE3 softmax weights (3)
    float* __restrict__ C, int N)
{
    __shared__ bf16 Ah[64][72], Al[64][72], Bh[64][72], Bl[64][72];

    const int m0 = blockIdx.x * 64;
    const int n0 = blockIdx.y * 64;
    const int tid = threadIdx.x;
    const int wave = tid >> 6;
    const int lane = tid & 63;
    const int wm = (wave >> 1) * 32;
    const int wn = (wave & 1) * 32;
    const int m16 = lane & 15;
    const int q   = lane >> 4;

    int scale = 0;
    if (DT_MODE) scale = (m0 < 2048) ? 0 : ((m0 < 3072) ? 1 : 2);
    const float* Wp = DT_MODE ? (W + (size_t)scale * 1024 * K) : W;
    const float* bias_p = (ACT == 3) ? (DT_MODE ? bias + (size_t)scale * N : bias) : nullptr;

    f4v acc[2][2];
#pragma unroll
    for (int i = 0; i < 2; i++)
#pragma unroll
        for (int j = 0; j < 2; j++)
#pragma unroll
            for (int r = 0; r < 4; r++) acc[i][j][r] = 0.f;

    const int cch = tid & 15;
    const int c4  = cch * 4;
    const int r0  = tid >> 4;

    // A row pointers (CTX_A: three upsample-indexed sources)
    const float* a0p[4]; const float* a1p[4]; const float* a2p[4];
#pragma unroll
    for (int p = 0; p < 4; p++) {
        int m = m0 + r0 + p * 16;
        if (CTX_A) {
            int b = m >> 10, t = m & 1023;
            a0p[p] = yy0 + (size_t)m * 1024 + c4;
            a1p[p] = yy1 + (size_t)((b << 9) + (t >> 1)) * 1024 + c4;
            a2p[p] = yy2 + (size_t)((b << 8) + (t >> 2)) * 1024 + c4;
        } else {
            a0p[p] = A + (size_t)m * lda + c4;
        }
    }
    const float* Bbase = Wp + (size_t)(n0 + r0) * K + c4;

    const int nkt = K >> 6;
    float4 ra[4], rb[4];
#pragma unroll
    for (int p = 0; p < 4; p++) {
        if (CTX_A) {
            float4 u = *reinterpret_cast<const float4*>(a0p[p]);
            float4 v = *reinterpret_cast<const float4*>(a1p[p]);
            float4 w = *reinterpret_cast<const float4*>(a2p[p]);
            ra[p] = make_float4((u.x + v.x + w.x) * (1.f / 3.f), (u.y + v.y + w.y) * (1.f / 3.f),
                                (u.z + v.z + w.z) * (1.f / 3.f), (u.w + v.w + w.w) * (1.f / 3.f));
        } else {
            ra[p] = *reinterpret_cast<const float4*>(a0p[p]);
        }
        rb[p] = *reinterpret_cast<const float4*>(Bbase + (size_t)(p * 16) * K);
    }

    for (int kt = 0; kt < nkt; kt++) {
        if (kt) __syncthreads();
#pragma unroll
        for (int p = 0; p < 4; p++) {
            int r = r0 + p * 16;
            split_store4(ra[p], &Ah[r][c4], &Al[r][c4]);
            split_store4(rb[p], &Bh[r][c4], &Bl[r][c4]);
        }
        __syncthreads();
        if (kt + 1 < nkt) {
            int off = (kt + 1) * 64;
#pragma unroll
            for (int p = 0; p < 4; p++) {
                if (CTX_A) {
                    float4 u = *reinterpret_cast<const float4*>(a0p[p] + off);
                    float4 v = *reinterpret_cast<const float4*>(a1p[p] + off);
                    float4 w = *reinterpret_cast<const float4*>(a2p[p] + off);
                    ra[p] = make_float4((u.x + v.x + w.x) * (1.f / 3.f), (u.y + v.y + w.y) * (1.f / 3.f),
                                        (u.z + v.z + w.z) * (1.f / 3.f), (u.w + v.w + w.w) * (1.f / 3.f));
                } else {
                    ra[p] = *reinterpret_cast<const float4*>(a0p[p] + off);
                }
                rb[p] = *reinterpret_cast<const float4*>(Bbase + off + (size_t)(p * 16) * K);
            }
        }
#pragma unroll
        for (int kk = 0; kk < 2; kk++) {
            const int col = kk * 32 + q * 8;
            s8v ah[2], al[2], bh[2], bl[2];
#pragma unroll
            for (int i = 0; i < 2; i++) {
                int ar = wm + i * 16 + m16;
                ah[i] = *reinterpret_cast<const s8v*>(&Ah[ar][col]);
                al[i] = *reinterpret_cast<const s8v*>(&Al[ar][col]);
                int br = wn + i * 16 + m16;
                bh[i] = *reinterpret_cast<const s8v*>(&Bh[br][col]);
                bl[i] = *reinterpret_cast<const s8v*>(&Bl[br][col]);
            }
#pragma unroll
            for (int i = 0; i < 2; i++)
#pragma unroll
                for (int j = 0; j < 2; j++) {
                    acc[i][j] = __builtin_amdgcn_mfma_f32_16x16x32_bf16(ah[i], bh[j], acc[i][j], 0, 0, 0);
                    acc[i][j] = __builtin_amdgcn_mfma_f32_16x16x32_bf16(al[i], bh[j], acc[i][j], 0, 0, 0);
                    acc[i][j] = __builtin_amdgcn_mfma_f32_16x16x32_bf16(ah[i], bl[j], acc[i][j], 0, 0, 0);
                }
        }
    }

    // GATE3 softmax weights
    float e0 = 0.f, e1 = 0.f, e2 = 0.f, inv = 0.f;
    if (GATE3) {
        float s0 = swp[0], s1 = swp[1], s2 = swp[2];
        float mx = fmaxf(s0, fmaxf(s1, s2));
        e0 = __expf(s0 - mx); e1 = __expf(s1 - mx); e2 = __expf(s2 - mx);
        inv = 1.f / (e0 + e1 + e2);
    }

    // Epilogue. D mapping (verified): row = q*4 + reg, col = lane&15.
#pragma unroll
    for (int i = 0; i < 2; i++) {
#pragma unroll
        for (int j = 0; j < 2; j++) {
#pragma unroll
            for (int r = 0; r < 4; r++) {
                int gm = m0 + wm + i * 16 + q * 4 + r;
                int gn = n0 + wn + j * 16 + m16;
                float v = acc[i][j][r];
                if (ACT == 3) { v += bias_p[gn]; v = (v > 20.f) ? v : __logf(1.f + __expf(v)); }
                else if (ACT == 1) v = siluf_(v);
                else if (ACT == 2) v = sigmoidf_(v);
                if (GATE3) {
                    int b = gm >> 10, t = gm & 1023;
                    float f = (e0 * yy0[(size_t)gm * 1024 + gn]
                             + e1 * yy1[(size_t)((b << 9) + (t >> 1)) * 1024 + gn]
                             + e2 * yy2[(size_t)((b << 8) + (t >> 2)) * 1024 + gn]) * inv;
                    v = f * v * siluf_(gxz[(size_t)gm * 2048 + 1024 + gn]);
                } else if (ADD_RES) {
                    v += res[(size_t)gm * N + gn];
                }
                C[(size_t)gm * N + gn] = v;
            }
        }
    }
}

// ---------------------------------------------------------------------------
// xproj MFMA: stacked M=3584, N=96 (clamped), K=1024, ldc=96. Grid (56,2).
// ---------------------------------------------------------------------------
__global__ __launch_bounds__(256) void xproj_mfma_kernel(
    const float* __restrict__ A, const float* __restrict__ xw,
    float* __restrict__ pj)
{
    const int K = 1024;
    __shared__ bf16 Ah[64][72], Al[64][72], Bh[64][72], Bl[64][72];

    const int m0 = blockIdx.x * 64;
    const int n0 = blockIdx.y * 64;
    const int tid = threadIdx.x;
    const int wave = tid >> 6;
    const int lane = tid & 63;
    const int wm = (wave >> 1) * 32;
    const int wn = (wave & 1) * 32;
    const int m16 = lane & 15;
    const int q   = lane >> 4;

    const int scale = (m0 < 2048) ? 0 : ((m0 < 3072) ? 1 : 2);
    const float* Wp = xw + (size_t)scale * 96 * K;

    f4v acc[2][2];
#pragma unroll
    for (int i = 0; i < 2; i++)
#pragma unroll
        for (int j = 0; j < 2; j++)
#pragma unroll
            for (int r = 0; r < 4; r++) acc[i][j][r] = 0.f;

    const int cch = tid & 15;
    const int c4  = cch * 4;
    const int r0  = tid >> 4;

    const float* Abase = A + (size_t)(m0 + r0) * K + c4;
    const float* Bbase = Wp + (size_t)(n0 + r0) * K + c4;
    bool bok[4];
#pragma unroll
    for (int p = 0; p < 4; p++) bok[p] = (n0 + r0 + p * 16) < 96;

    const int nkt = K >> 6;
    float4 ra[4], rb[4];
    const float4 zero4 = make_float4(0.f, 0.f, 0.f, 0.f);
#pragma unroll
    for (int p = 0; p < 4; p++) {
        ra[p] = *reinterpret_cast<const float4*>(Abase + (size_t)(p * 16) * K);
        rb[p] = bok[p] ? *reinterpret_cast<const float4*>(Bbase + (size_t)(p * 16) * K) : zero4;
    }

    for (int kt = 0; kt < nkt; kt++) {
        if (kt) __syncthreads();
#pragma unroll
        for (int p = 0; p < 4; p++) {
            int r = r0 + p * 16;
            split_store4(ra[p], &Ah[r][c4], &Al[r][c4]);
            split_store4(rb[p], &Bh[r][c4], &Bl[r][c4]);
        }
        __syncthreads();
        if (kt + 1 < nkt) {
            int off = (kt + 1) * 64;
#pragma unroll
            for (int p = 0; p < 4; p++) {
                ra[p] = *reinterpret_cast<const float4*>(Abase + off + (size_t)(p * 16) * K);
                rb[p] = bok[p] ? *reinterpret_cast<const float4*>(Bbase + off + (size_t)(p * 16) * K) : zero4;
            }
        }
#pragma unroll
        for (int kk = 0; kk < 2; kk++) {
            const int col = kk * 32 + q * 8;
            s8v ah[2], al[2], bh[2], bl[2];
#pragma unroll
            for (int i = 0; i < 2; i++) {
                int ar = wm + i * 16 + m16;
                ah[i] = *reinterpret_cast<const s8v*>(&Ah[ar][col]);
                al[i] = *reinterpret_cast<const s8v*>(&Al[ar][col]);
                int br = wn + i * 16 + m16;
                bh[i] = *reinterpret_cast<const s8v*>(&Bh[br][col]);
                bl[i] = *reinterpret_cast<const s8v*>(&Bl[br][col]);
            }
#pragma unroll
            for (int i = 0; i < 2; i++)
#pragma unroll
                for (int j = 0; j < 2; j++) {
                    acc[i][j] = __builtin_amdgcn_mfma_f32_16x16x32_bf16(ah[i], bh[j], acc[i][j], 0, 0, 0);
                    acc[i][j] = __builtin_amdgcn_mfma_f32_16x16x32_bf16(al[i], bh[j], acc[i][j], 0, 0, 0);
                    acc[i][j] = __builtin_amdgcn_mfma_f32_16x16x32_bf16(ah[i], bl[j], acc[i][j], 0, 0, 0);
                }
        }
    }

#pragma unroll
    for (int i = 0; i < 2; i++) {
#pragma unroll
        for (int j = 0; j < 2; j++) {
            int gn = n0 + wn + j * 16 + m16;
            if (gn >= 96) continue;
#pragma unroll
            for (int r = 0; r < 4; r++) {
                int gm = m0 + wm + i * 16 + q * 4 + r;
                pj[(size_t)gm * 96 + gn] = acc[i][j][r];
            }
        }
    }
}

// ---------------------------------------------------------------------------
// Fused downsample + depthwise causal conv(K=4) + bias + SiLU, all 3 scales.
// ---------------------------------------------------------------------------
__global__ void conv_fused_kernel(const float* __restrict__ xz,
                                  const float* __restrict__ cw,
                                  const float* __restrict__ cb,
                                  float* __restrict__ xc)
{
    int idx = blockIdx.x * blockDim.x + threadIdx.x;
    if (idx >= 3670016) return;
    int s, rel;
    if (idx < 2097152)      { s = 0; rel = idx; }
    else if (idx < 3145728) { s = 1; rel = idx - 2097152; }
    else                    { s = 2; rel = idx - 3145728; }
    int c = rel & 1023;
    int row = rel >> 10;
    int Ts = 1024 >> s;
    int b = row / Ts;
    int t = row - b * Ts;
    const float* base = xz + (size_t)(b * 1024) * 2048 + c;

    float acc = cb[s * 1024 + c];
#pragma unroll
    for (int k = 0; k < 4; k++) {
        int tau = t - 3 + k;
        if (tau < 0) continue;
        float xv;
        if (s == 0) {
            xv = base[(size_t)tau * 2048];
        } else if (s == 1) {
            xv = 0.5f * (base[(size_t)(2 * tau) * 2048] + base[(size_t)(2 * tau + 1) * 2048]);
        } else {
            xv = 0.25f * (base[(size_t)(4 * tau) * 2048] + base[(size_t)(4 * tau + 1) * 2048]
                        + base[(size_t)(4 * tau + 2) * 2048] + base[(size_t)(4 * tau + 3) * 2048]);
        }
        acc = fmaf(cw[(s * 1024 + c) * 4 + k], xv, acc);
    }
    xc[idx] = siluf_(acc);
}

// ---------------------------------------------------------------------------
// Chunked selective scan, CHUNK=16, 896 blocks/pass.
// State layout: [s][b][chunk][j][d] (d fastest). soff: s0=0, s1=2097152, s2=3145728.
// hbuf is write-once (pass1). Inclusive carries go to a SEPARATE cbuf
// (no in-place mutation anywhere). pass2 reads cbuf[chunk-1] only.
// ---------------------------------------------------------------------------
__device__ __forceinline__ void scan_decode(int blk, int& s, int& nchunk, int& Ts,
                                            int& dquad, int& chunk, int& b, size_t& soff)
{
    int local;
    if (blk < 512)      { s = 0; local = blk;       soff = 0; }
    else if (blk < 768) { s = 1; local = blk - 512; soff = 2097152; }
    else                { s = 2; local = blk - 768; soff = 3145728; }
    nchunk = 64 >> s;
    Ts = 1024 >> s;
    dquad = local & 3;
    chunk = (local >> 2) & (nchunk - 1);
    b = local >> (8 - s);
}

__global__ __launch_bounds__(256) void scan_pass1(
    const float* __restrict__ dt0, const float* __restrict__ xc0, const float* __restrict__ pj0,
    const float* __restrict__ dt1, const float* __restrict__ xc1, const float* __restrict__ pj1,
    const float* __restrict__ dt2, const float* __restrict__ xc2, const float* __restrict__ pj2,
    const float* __restrict__ A_log,
    float* __restrict__ prodA_buf, float* __restrict__ h_buf)
{
    int s, nchunk, Ts, dquad, chunk, b; size_t soff;
    scan_decode(blockIdx.x, s, nchunk, Ts, dquad, chunk, b, soff);
    const float* dt = (s == 0) ? dt0 : (s == 1) ? dt1 : dt2;
    const float* xc = (s == 0) ? xc0 : (s == 1) ? xc1 : xc2;
    const float* pj = (s == 0) ? pj0 : (s == 1) ? pj1 : pj2;

    const int d = dquad * 256 + threadIdx.x;
    const size_t rowbase = (size_t)b * Ts;
    const int t0 = chunk * CHUNK;

    float Acoef[16], h[16], p[16];
#pragma unroll
    for (int j = 0; j < 16; j++) {
        Acoef[j] = -__expf(A_log[((size_t)(s * DINNER + d)) * 16 + j]);
        h[j] = 0.f; p[j] = 1.f;
    }

    __shared__ float bcB[CHUNK][16];
    if (threadIdx.x < CHUNK * 16) {
        int i = threadIdx.x >> 4, jj = threadIdx.x & 15;
        bcB[i][jj] = pj[(rowbase + t0 + i) * 96 + 64 + jj];
    }
    __syncthreads();

    size_t trow = (rowbase + t0) * DINNER + d;
    float dtv = dt[trow];
    float xv  = xc[trow];
    for (int i = 0; i < CHUNK; i++) {
        float dtn = 0.f, xvn = 0.f;
        if (i + 1 < CHUNK) {
            size_t tn = trow + (size_t)(i + 1) * DINNER;
            dtn = dt[tn];
            xvn = xc[tn];
        }
#pragma unroll
        for (int j = 0; j < 16; j++) {
            float dA  = fmaxf(__expf(dtv * Acoef[j]), 1e-38f);
            float dbx = fmaxf(dtv * bcB[i][j] * xv, 1e-38f);
            h[j] = fmaf(dA, h[j], dbx);
            p[j] *= dA;
        }
        dtv = dtn; xv = xvn;
    }

    size_t base = soff + (size_t)((b * nchunk + chunk) * 16) * 1024 + d;
#pragma unroll
    for (int j = 0; j < 16; j++) {
        prodA_buf[base + (size_t)j * 1024] = p[j];
        h_buf[base + (size_t)j * 1024] = h[j];
    }
}

// Out-of-place inclusive combine: cbuf[c] = prodA[c]*cbuf[c-1] + hbuf[c]
// (computed in registers; hbuf is never modified).
// 96 blocks = (s:3) x (b:2, dquad:4, jq:4). 4 independent j-chains per thread.
__global__ __launch_bounds__(256) void scan_carry(
    const float* __restrict__ prodA_buf, const float* __restrict__ h_buf,
    float* __restrict__ c_buf)
{
    int s = blockIdx.x >> 5;
    int local = blockIdx.x & 31;
    int jq = local & 3;
    int dquad = (local >> 2) & 3;
    int b = local >> 4;
    size_t soff = (s == 0) ? 0 : ((s == 1) ? 2097152 : 3145728);
    int nchunk = 64 >> s;

    const int d = dquad * 256 + threadIdx.x;
    float H[4] = {0.f, 0.f, 0.f, 0.f};
    for (int c = 0; c < nchunk; c++) {
        size_t base = soff + (size_t)((b * nchunk + c) * 16 + jq * 4) * 1024 + d;
#pragma unroll
        for (int jj = 0; jj < 4; jj++) {
            float p = prodA_buf[base + (size_t)jj * 1024];
            float h = h_buf[base + (size_t)jj * 1024];
            H[jj] = fmaf(p, H[jj], h);
            c_buf[base + (size_t)jj * 1024] = H[jj];
        }
    }
}

__global__ __launch_bounds__(256) void scan_pass2(
    const float* __restrict__ dt0, const float* __restrict__ xc0,
    const float* __restrict__ pj0, float* __restrict__ y0,
    const float* __restrict__ dt1, const float* __restrict__ xc1,
    const float* __restrict__ pj1, float* __restrict__ y1,
    const float* __restrict__ dt2, const float* __restrict__ xc2,
    const float* __restrict__ pj2, float* __restrict__ y2,
    const float* __restrict__ A_log, const float* __restrict__ D_p,
    const float* __restrict__ c_buf)
{
    int s, nchunk, Ts, dquad, chunk, b; size_t soff;
    scan_decode(blockIdx.x, s, nchunk, Ts, dquad, chunk, b, soff);
    const float* dt = (s == 0) ? dt0 : (s == 1) ? dt1 : dt2;
    const float* xc = (s == 0) ? xc0 : (s == 1) ? xc1 : xc2;
    const float* pj = (s == 0) ? pj0 : (s == 1) ? pj1 : pj2;
    float* y        = (s == 0) ? y0  : (s == 1) ? y1  : y2;

    const int d = dquad * 256 + threadIdx.x;
    const size_t rowbase = (size_t)b * Ts;
    const int t0 = chunk * CHUNK;

    float Acoef[16], h[16];
#pragma unroll
    for (int j = 0; j < 16; j++) {
        Acoef[j] = -__expf(A_log[((size_t)(s * DINNER + d)) * 16 + j]);
        h[j] = 0.f;
    }
    const float Dp = D_p[s * DINNER + d];

    if (chunk > 0) {   // inclusive state of chunk-1 (one 16-load read)
        size_t cb = soff + (size_t)((b * nchunk + chunk - 1) * 16) * 1024 + d;
#pragma unroll
        for (int j = 0; j < 16; j++)
            h[j] = c_buf[cb + (size_t)j * 1024];
    }

    __shared__ float bc[CHUNK][32];
    for (int u = threadIdx.x; u < CHUNK * 32; u += 256) {
        int i = u >> 5, jj = u & 31;
        bc[i][jj] = pj[(rowbase + t0 + i) * 96 + 64 + jj];
    }
    __syncthreads();

    size_t trow = (rowbase + t0) * DINNER + d;
    float dtv = dt[trow];
    float xv  = xc[trow];
    for (int i = 0; i < CHUNK; i++) {
        float dtn = 0.f, xvn = 0.f;
        if (i + 1 < CHUNK) {
            size_t tn = trow + (size_t)(i + 1) * DINNER;
            dtn = dt[tn];
            xvn = xc[tn];
        }
        float accy = 0.f;
#pragma unroll
        for (int j = 0; j < 16; j++) {
            float dA  = fmaxf(__expf(dtv * Acoef[j]), 1e-38f);
            float dbx = fmaxf(dtv * bc[i][j] * xv, 1e-38f);
            h[j] = fmaf(dA, h[j], dbx);
            accy = fmaf(bc[i][16 + j], h[j], accy);
        }
        y[trow + (size_t)i * DINNER] = accy + Dp * xv;
        dtv = dtn; xv = xvn;
    }
}

// ---------------------------------------------------------------------------
__global__ __launch_bounds__(256) void ln_kernel(
    const float* __restrict__ yin, const float* __restrict__ gamma,
    const float* __restrict__ beta, float* __restrict__ out)
{
    int token = blockIdx.x;
    int tid = threadIdx.x;
    const float* row = yin + (size_t)token * DIMSZ;
    float v0 = row[tid], v1 = row[tid + 256];
    __shared__ float s1[256], s2[256];
    s1[tid] = v0 + v1;
    s2[tid] = v0 * v0 + v1 * v1;
    __syncthreads();
    for (int off = 128; off > 0; off >>= 1) {
        if (tid < off) { s1[tid] += s1[tid + off]; s2[tid] += s2[tid + off]; }
        __syncthreads();
    }
    float mu = s1[0] * (1.f / 512.f);
    float var = s2[0] * (1.f / 512.f) - mu * mu;
    float rstd = rsqrtf(var + 1e-5f);
    float* orow = out + (size_t)token * DIMSZ;
    orow[tid]       = (v0 - mu) * rstd * gamma[tid]       + beta[tid];
    orow[tid + 256] = (v1 - mu) * rstd * gamma[tid + 256] + beta[tid + 256];
}

// ---------------------------------------------------------------------------
extern "C" void kernel_launch(void* const* d_in, const int* in_sizes, int n_in,
                              void* d_out, int out_size, void* d_ws, size_t ws_size,
                              hipStream_t stream)
{
    const float* x         = (const float*)d_in[0];
    const float* in_proj_w = (const float*)d_in[1];
    const float* conv_w    = (const float*)d_in[2];
    const float* conv_b    = (const float*)d_in[3];
    const float* xproj_w   = (const float*)d_in[4];
    const float* dtproj_w  = (const float*)d_in[5];
    const float* dtproj_b  = (const float*)d_in[6];
    const float* A_log     = (const float*)d_in[7];
    const float* D_p       = (const float*)d_in[8];
    const float* scale_w   = (const float*)d_in[9];
    const float* cg_w1     = (const float*)d_in[10];
    const float* cg_w2     = (const float*)d_in[11];
    const float* out_pw    = (const float*)d_in[12];
    const float* ln_gamma  = (const float*)d_in[13];
    const float* ln_beta   = (const float*)d_in[14];
    float* out = (float*)d_out;

    float* ws = (float*)d_ws;
    // f32 workspace layout (element offsets)
    float* xz    = ws;                       // 4,194,304  (2048 x 2048)
    float* xc0   = xz    + 4194304;          // xc stacked 3584x1024
    float* xc1   = xc0   + 2097152;
    float* xc2   = xc1   + 1048576;
    float* pj0   = xc2   + 524288;           // pj stacked 3584x96
    float* pj1   = pj0   + 196608;
    float* pj2   = pj1   + 98304;
    float* dt0   = pj2   + 49152;            // dt stacked 3584x1024
    float* dt1   = dt0   + 2097152;
    float* dt2   = dt1   + 1048576;
    float* y0    = dt2   + 524288;           // y per scale
    float* y1    = y0    + 2097152;
    float* y2    = y1    + 1048576;
    float* prodA = y2    + 524288;           // 3,670,016 (CHUNK=16 states)
    float* hbuf  = prodA + 3670016;          // 3,670,016 (write-once)
    float* cbuf  = hbuf  + 3670016;          // 3,670,016 (inclusive carries)
    // total: 26,558,464 floats = 106.2 MB

    // Overlays (lifetime-checked):
    float* h1     = dt1;   // cg1 out (2048x512); dt dead after pass2
    float* fusedg = dt0;   // cg2 out (2048x1024); y stays live for cg2
    float* outpre = xc1;   // out_proj out; xc dead after pass2

    // P1) in_proj: xz = x @ in_proj_w^T  (M=2048,N=2048,K=512) — 1024 blocks
    mgemm_kernel<0, false, false, false, false><<<dim3(32, 32), 256, 0, stream>>>(
        x, DIMSZ, DIMSZ, in_proj_w, nullptr, nullptr, nullptr,
        nullptr, nullptr, nullptr, nullptr, xz, 2048);

    // P2) fused downsample+conv+SiLU — 14336 blocks
    conv_fused_kernel<<<14336, 256, 0, stream>>>(xz, conv_w, conv_b, xc0);

    // P3) xproj stacked MFMA (M=3584,N=96,K=1024) — 112 blocks
    xproj_mfma_kernel<<<dim3(56, 2), 256, 0, stream>>>(xc0, xproj_w, pj0);

    // P4) dtproj stacked (M=3584,N=1024,K=64, A=pj cols 0..63) — 896 blocks
    mgemm_kernel<3, false, true, false, false><<<dim3(56, 16), 256, 0, stream>>>(
        pj0, 96, DTRANK, dtproj_w, dtproj_b, nullptr, nullptr,
        nullptr, nullptr, nullptr, nullptr, dt0, 1024);

    // P5) scan pass1 — 896 blocks (CHUNK=16)
    scan_pass1<<<896, 256, 0, stream>>>(dt0, xc0, pj0, dt1, xc1, pj1,
                                        dt2, xc2, pj2, A_log, prodA, hbuf);
    // P6) carry combine (out-of-place into cbuf) — 96 blocks
    scan_carry<<<96, 256, 0, stream>>>(prodA, hbuf, cbuf);
    // P7) scan pass2 (direct carry from cbuf) — 896 blocks
    scan_pass2<<<896, 256, 0, stream>>>(dt0, xc0, pj0, y0, dt1, xc1, pj1, y1,
                                        dt2, xc2, pj2, y2, A_log, D_p, cbuf);

    // P8) cg1 (ctx on-the-fly from y0/y1/y2): h1 = silu(ctx @ cg_w1^T)
    //     (N=512,K=1024) — 256 blocks
    mgemm_kernel<1, false, false, true, false><<<dim3(32, 8), 256, 0, stream>>>(
        nullptr, DINNER, DINNER, cg_w1, nullptr, nullptr, nullptr,
        y0, y1, y2, nullptr, h1, 512);

    // P9) cg2 + softmax-fuse + gate: fusedg = fused(y,sw) * sigmoid(h1@cg_w2^T) * silu(gate)
    //     (N=1024,K=512) — 512 blocks
    mgemm_kernel<2, false, false, false, true><<<dim3(32, 16), 256, 0, stream>>>(
        h1, 512, 512, cg_w2, nullptr, nullptr, xz,
        y0, y1, y2, scale_w, fusedg, 1024);

    // P10) out_proj + residual: outpre = fusedg @ out_pw^T + x (N=512,K=1024)
    mgemm_kernel<0, true, false, false, false><<<dim3(32, 8), 256, 0, stream>>>(
        fusedg, DINNER, DINNER, out_pw, nullptr, x, nullptr,
        nullptr, nullptr, nullptr, nullptr, outpre, 512);

    // P11) LayerNorm
    ln_kernel<<<BATCH * SEQ, 256, 0, stream>>>(outpre, ln_gamma, ln_beta, out);
}

// Round 12
// 296.283 us; speedup vs baseline: 1.0046x; 1.0046x over previous
//
#include <hip/hip_runtime.h>
#include <hip/hip_bf16.h>

// HierarchicalMambaBlock: B=2,T=1024,DIM=512 -> D_INNER=1024, DT_RANK=64, D_STATE=16
// All tensors f32. GEMMs on MFMA via ON-THE-FLY split precision:
// stage f32 tiles into LDS as hi/lo bf16; acc += Ah*Bh + Al*Bh + Ah*Bl (~f32 accurate).
// Scan: R10-proven structure (CHUNK=32, fold-in-pass2) with j-dimension split
// across 2 blocks (8 states each); y = yA + yB recombined in cg1/cg2 reads.
#define BATCH   2
#define SEQ     1024
#define DIMSZ   512
#define DINNER  1024
#define DTRANK  64
#define DSTATE  16
#define CHUNK   32

typedef __hip_bfloat16 bf16;
typedef __attribute__((ext_vector_type(8))) short s8v;   // 8 bf16 MFMA frag
typedef __attribute__((ext_vector_type(4))) float f4v;   // 4 f32 acc

__device__ __forceinline__ float sigmoidf_(float x) { return 1.f / (1.f + __expf(-x)); }
__device__ __forceinline__ float siluf_(float x) { return x * sigmoidf_(x); }
__device__ __forceinline__ void split2(float v, bf16& hi, bf16& lo) {
    hi = __float2bfloat16(v);
    lo = __float2bfloat16(v - __bfloat162float(hi));
}
__device__ __forceinline__ void split_store4(const float4 v,
                                             bf16* __restrict__ ph,
                                             bf16* __restrict__ pl) {
    union { bf16 b[4]; uint2 u; } H, L;
    split2(v.x, H.b[0], L.b[0]); split2(v.y, H.b[1], L.b[1]);
    split2(v.z, H.b[2], L.b[2]); split2(v.w, H.b[3], L.b[3]);
    *reinterpret_cast<uint2*>(ph) = H.u;
    *reinterpret_cast<uint2*>(pl) = L.u;
}

// ---------------------------------------------------------------------------
// MFMA GEMM, 64x64 tile, BK=64 f32, 4 waves (each 32x32 of 16x16x32 frags),
// register prefetch of next K-tile. A,W f32; split to hi/lo at LDS stage.
// ACT: 0 none, 1 silu, 2 sigmoid, 3 bias+softplus
// DT_MODE: stacked dtproj (M=3584): per-block W/bias select by scale
// CTX_A:  A[m,k] = ((yA0+yB0)[m,k] + (yA1+yB1)[up(m),k] + (yA2+yB2)[up(m),k])/3
// GATE3:  v = softmax_fused(yA+yB, sw)[gm,gn] * v * silu(xz gate)
// Requires: M,N multiples of 64, K multiple of 64, lda%4==0.
// ---------------------------------------------------------------------------
template <int ACT, bool ADD_RES, bool DT_MODE, bool CTX_A, bool GATE3>
__global__ __launch_bounds__(256) void mgemm_kernel(
    const float* __restrict__ A, int lda, int K,
    const float* __restrict__ W,            // ldw = K
    const float* __restrict__ bias,
    const float* __restrict__ res,          // residual (ADD_RES)
    const float* __restrict__ gxz,          // xz (GATE3)
    const float* __restrict__ ya0, const float* __restrict__ ya1,
    const float* __restrict__ ya2,          // CTX_A / GATE3 (partial A)
    const float* __restrict__ yb0, const float* __restrict__ yb1,
    const float* __restrict__ yb2,          // CTX_A / GATE3 (partial B)
    const float* __restrict__ swp,          // GATE3 softmax weights (3)
    float* __restrict__ C, int N)
{
    __shared__ bf16 Ah[64][72], Al[64][72], Bh[64][72], Bl[64][72];

    const int m0 = blockIdx.x * 64;
    const int n0 = blockIdx.y * 64;
    const int tid = threadIdx.x;
    const int wave = tid >> 6;
    const int lane = tid & 63;
    const int wm = (wave >> 1) * 32;
    const int wn = (wave & 1) * 32;
    const int m16 = lane & 15;
    const int q   = lane >> 4;

    int scale = 0;
    if (DT_MODE) scale = (m0 < 2048) ? 0 : ((m0 < 3072) ? 1 : 2);
    const float* Wp = DT_MODE ? (W + (size_t)scale * 1024 * K) : W;
    const float* bias_p = (ACT == 3) ? (DT_MODE ? bias + (size_t)scale * N : bias) : nullptr;

    f4v acc[2][2];
#pragma unroll
    for (int i = 0; i < 2; i++)
#pragma unroll
        for (int j = 0; j < 2; j++)
#pragma unroll
            for (int r = 0; r < 4; r++) acc[i][j][r] = 0.f;

    const int cch = tid & 15;
    const int c4  = cch * 4;
    const int r0  = tid >> 4;

    // A row offsets (CTX_A: upsample-indexed partial sums)
    size_t off0[4], off1[4], off2[4];
    const float* a0p[4];
#pragma unroll
    for (int p = 0; p < 4; p++) {
        int m = m0 + r0 + p * 16;
        if (CTX_A) {
            int b = m >> 10, t = m & 1023;
            off0[p] = (size_t)m * 1024 + c4;
            off1[p] = (size_t)((b << 9) + (t >> 1)) * 1024 + c4;
            off2[p] = (size_t)((b << 8) + (t >> 2)) * 1024 + c4;
        } else {
            a0p[p] = A + (size_t)m * lda + c4;
        }
    }
    const float* Bbase = Wp + (size_t)(n0 + r0) * K + c4;

    const int nkt = K >> 6;
    float4 ra[4], rb[4];
#pragma unroll
    for (int p = 0; p < 4; p++) {
        if (CTX_A) {
            float4 u0 = *reinterpret_cast<const float4*>(ya0 + off0[p]);
            float4 v0 = *reinterpret_cast<const float4*>(yb0 + off0[p]);
            float4 u1 = *reinterpret_cast<const float4*>(ya1 + off1[p]);
            float4 v1 = *reinterpret_cast<const float4*>(yb1 + off1[p]);
            float4 u2 = *reinterpret_cast<const float4*>(ya2 + off2[p]);
            float4 v2 = *reinterpret_cast<const float4*>(yb2 + off2[p]);
            ra[p] = make_float4(
                (u0.x + v0.x + u1.x + v1.x + u2.x + v2.x) * (1.f / 3.f),
                (u0.y + v0.y + u1.y + v1.y + u2.y + v2.y) * (1.f / 3.f),
                (u0.z + v0.z + u1.z + v1.z + u2.z + v2.z) * (1.f / 3.f),
                (u0.w + v0.w + u1.w + v1.w + u2.w + v2.w) * (1.f / 3.f));
        } else {
            ra[p] = *reinterpret_cast<const float4*>(a0p[p]);
        }
        rb[p] = *reinterpret_cast<const float4*>(Bbase + (size_t)(p * 16) * K);
    }

    for (int kt = 0; kt < nkt; kt++) {
        if (kt) __syncthreads();
#pragma unroll
        for (int p = 0; p < 4; p++) {
            int r = r0 + p * 16;
            split_store4(ra[p], &Ah[r][c4], &Al[r][c4]);
            split_store4(rb[p], &Bh[r][c4], &Bl[r][c4]);
        }
        __syncthreads();
        if (kt + 1 < nkt) {
            int off = (kt + 1) * 64;
#pragma unroll
            for (int p = 0; p < 4; p++) {
                if (CTX_A) {
                    float4 u0 = *reinterpret_cast<const float4*>(ya0 + off0[p] + off);
                    float4 v0 = *reinterpret_cast<const float4*>(yb0 + off0[p] + off);
                    float4 u1 = *reinterpret_cast<const float4*>(ya1 + off1[p] + off);
                    float4 v1 = *reinterpret_cast<const float4*>(yb1 + off1[p] + off);
                    float4 u2 = *reinterpret_cast<const float4*>(ya2 + off2[p] + off);
                    float4 v2 = *reinterpret_cast<const float4*>(yb2 + off2[p] + off);
                    ra[p] = make_float4(
                        (u0.x + v0.x + u1.x + v1.x + u2.x + v2.x) * (1.f / 3.f),
                        (u0.y + v0.y + u1.y + v1.y + u2.y + v2.y) * (1.f / 3.f),
                        (u0.z + v0.z + u1.z + v1.z + u2.z + v2.z) * (1.f / 3.f),
                        (u0.w + v0.w + u1.w + v1.w + u2.w + v2.w) * (1.f / 3.f));
                } else {
                    ra[p] = *reinterpret_cast<const float4*>(a0p[p] + off);
                }
                rb[p] = *reinterpret_cast<const float4*>(Bbase + off + (size_t)(p * 16) * K);
            }
        }
#pragma unroll
        for (int kk = 0; kk < 2; kk++) {
            const int col = kk * 32 + q * 8;
            s8v ah[2], al[2], bh[2], bl[2];
#pragma unroll
            for (int i = 0; i < 2; i++) {
                int ar = wm + i * 16 + m16;
                ah[i] = *reinterpret_cast<const s8v*>(&Ah[ar][col]);
                al[i] = *reinterpret_cast<const s8v*>(&Al[ar][col]);
                int br = wn + i * 16 + m16;
                bh[i] = *reinterpret_cast<const s8v*>(&Bh[br][col]);
                bl[i] = *reinterpret_cast<const s8v*>(&Bl[br][col]);
            }
#pragma unroll
            for (int i = 0; i < 2; i++)
#pragma unroll
                for (int j = 0; j < 2; j++) {
                    acc[i][j] = __builtin_amdgcn_mfma_f32_16x16x32_bf16(ah[i], bh[j], acc[i][j], 0, 0, 0);
                    acc[i][j] = __builtin_amdgcn_mfma_f32_16x16x32_bf16(al[i], bh[j], acc[i][j], 0, 0, 0);
                    acc[i][j] = __builtin_amdgcn_mfma_f32_16x16x32_bf16(ah[i], bl[j], acc[i][j], 0, 0, 0);
                }
        }
    }

    // GATE3 softmax weights
    float e0 = 0.f, e1 = 0.f, e2 = 0.f, inv = 0.f;
    if (GATE3) {
        float s0 = swp[0], s1 = swp[1], s2 = swp[2];
        float mx = fmaxf(s0, fmaxf(s1, s2));
        e0 = __expf(s0 - mx); e1 = __expf(s1 - mx); e2 = __expf(s2 - mx);
        inv = 1.f / (e0 + e1 + e2);
    }

    // Epilogue. D mapping (verified): row = q*4 + reg, col = lane&15.
#pragma unroll
    for (int i = 0; i < 2; i++) {
#pragma unroll
        for (int j = 0; j < 2; j++) {
#pragma unroll
            for (int r = 0; r < 4; r++) {
                int gm = m0 + wm + i * 16 + q * 4 + r;
                int gn = n0 + wn + j * 16 + m16;
                float v = acc[i][j][r];
                if (ACT == 3) { v += bias_p[gn]; v = (v > 20.f) ? v : __logf(1.f + __expf(v)); }
                else if (ACT == 1) v = siluf_(v);
                else if (ACT == 2) v = sigmoidf_(v);
                if (GATE3) {
                    int b = gm >> 10, t = gm & 1023;
                    size_t i0 = (size_t)gm * 1024 + gn;
                    size_t i1 = (size_t)((b << 9) + (t >> 1)) * 1024 + gn;
                    size_t i2 = (size_t)((b << 8) + (t >> 2)) * 1024 + gn;
                    float f = (e0 * (ya0[i0] + yb0[i0])
                             + e1 * (ya1[i1] + yb1[i1])
                             + e2 * (ya2[i2] + yb2[i2])) * inv;
                    v = f * v * siluf_(gxz[(size_t)gm * 2048 + 1024 + gn]);
                } else if (ADD_RES) {
                    v += res[(size_t)gm * N + gn];
                }
                C[(size_t)gm * N + gn] = v;
            }
        }
    }
}

// ---------------------------------------------------------------------------
// xproj MFMA: stacked M=3584, N=96 (clamped), K=1024, ldc=96. Grid (56,2).
// ---------------------------------------------------------------------------
__global__ __launch_bounds__(256) void xproj_mfma_kernel(
    const float* __restrict__ A, const float* __restrict__ xw,
    float* __restrict__ pj)
{
    const int K = 1024;
    __shared__ bf16 Ah[64][72], Al[64][72], Bh[64][72], Bl[64][72];

    const int m0 = blockIdx.x * 64;
    const int n0 = blockIdx.y * 64;
    const int tid = threadIdx.x;
    const int wave = tid >> 6;
    const int lane = tid & 63;
    const int wm = (wave >> 1) * 32;
    const int wn = (wave & 1) * 32;
    const int m16 = lane & 15;
    const int q   = lane >> 4;

    const int scale = (m0 < 2048) ? 0 : ((m0 < 3072) ? 1 : 2);
    const float* Wp = xw + (size_t)scale * 96 * K;

    f4v acc[2][2];
#pragma unroll
    for (int i = 0; i < 2; i++)
#pragma unroll
        for (int j = 0; j < 2; j++)
#pragma unroll
            for (int r = 0; r < 4; r++) acc[i][j][r] = 0.f;

    const int cch = tid & 15;
    const int c4  = cch * 4;
    const int r0  = tid >> 4;

    const float* Abase = A + (size_t)(m0 + r0) * K + c4;
    const float* Bbase = Wp + (size_t)(n0 + r0) * K + c4;
    bool bok[4];
#pragma unroll
    for (int p = 0; p < 4; p++) bok[p] = (n0 + r0 + p * 16) < 96;

    const int nkt = K >> 6;
    float4 ra[4], rb[4];
    const float4 zero4 = make_float4(0.f, 0.f, 0.f, 0.f);
#pragma unroll
    for (int p = 0; p < 4; p++) {
        ra[p] = *reinterpret_cast<const float4*>(Abase + (size_t)(p * 16) * K);
        rb[p] = bok[p] ? *reinterpret_cast<const float4*>(Bbase + (size_t)(p * 16) * K) : zero4;
    }

    for (int kt = 0; kt < nkt; kt++) {
        if (kt) __syncthreads();
#pragma unroll
        for (int p = 0; p < 4; p++) {
            int r = r0 + p * 16;
            split_store4(ra[p], &Ah[r][c4], &Al[r][c4]);
            split_store4(rb[p], &Bh[r][c4], &Bl[r][c4]);
        }
        __syncthreads();
        if (kt + 1 < nkt) {
            int off = (kt + 1) * 64;
#pragma unroll
            for (int p = 0; p < 4; p++) {
                ra[p] = *reinterpret_cast<const float4*>(Abase + off + (size_t)(p * 16) * K);
                rb[p] = bok[p] ? *reinterpret_cast<const float4*>(Bbase + off + (size_t)(p * 16) * K) : zero4;
            }
        }
#pragma unroll
        for (int kk = 0; kk < 2; kk++) {
            const int col = kk * 32 + q * 8;
            s8v ah[2], al[2], bh[2], bl[2];
#pragma unroll
            for (int i = 0; i < 2; i++) {
                int ar = wm + i * 16 + m16;
                ah[i] = *reinterpret_cast<const s8v*>(&Ah[ar][col]);
                al[i] = *reinterpret_cast<const s8v*>(&Al[ar][col]);
                int br = wn + i * 16 + m16;
                bh[i] = *reinterpret_cast<const s8v*>(&Bh[br][col]);
                bl[i] = *reinterpret_cast<const s8v*>(&Bl[br][col]);
            }
#pragma unroll
            for (int i = 0; i < 2; i++)
#pragma unroll
                for (int j = 0; j < 2; j++) {
                    acc[i][j] = __builtin_amdgcn_mfma_f32_16x16x32_bf16(ah[i], bh[j], acc[i][j], 0, 0, 0);
                    acc[i][j] = __builtin_amdgcn_mfma_f32_16x16x32_bf16(al[i], bh[j], acc[i][j], 0, 0, 0);
                    acc[i][j] = __builtin_amdgcn_mfma_f32_16x16x32_bf16(ah[i], bl[j], acc[i][j], 0, 0, 0);
                }
        }
    }

#pragma unroll
    for (int i = 0; i < 2; i++) {
#pragma unroll
        for (int j = 0; j < 2; j++) {
            int gn = n0 + wn + j * 16 + m16;
            if (gn >= 96) continue;
#pragma unroll
            for (int r = 0; r < 4; r++) {
                int gm = m0 + wm + i * 16 + q * 4 + r;
                pj[(size_t)gm * 96 + gn] = acc[i][j][r];
            }
        }
    }
}

// ---------------------------------------------------------------------------
// Fused downsample + depthwise causal conv(K=4) + bias + SiLU, all 3 scales.
// ---------------------------------------------------------------------------
__global__ void conv_fused_kernel(const float* __restrict__ xz,
                                  const float* __restrict__ cw,
                                  const float* __restrict__ cb,
                                  float* __restrict__ xc)
{
    int idx = blockIdx.x * blockDim.x + threadIdx.x;
    if (idx >= 3670016) return;
    int s, rel;
    if (idx < 2097152)      { s = 0; rel = idx; }
    else if (idx < 3145728) { s = 1; rel = idx - 2097152; }
    else                    { s = 2; rel = idx - 3145728; }
    int c = rel & 1023;
    int row = rel >> 10;
    int Ts = 1024 >> s;
    int b = row / Ts;
    int t = row - b * Ts;
    const float* base = xz + (size_t)(b * 1024) * 2048 + c;

    float acc = cb[s * 1024 + c];
#pragma unroll
    for (int k = 0; k < 4; k++) {
        int tau = t - 3 + k;
        if (tau < 0) continue;
        float xv;
        if (s == 0) {
            xv = base[(size_t)tau * 2048];
        } else if (s == 1) {
            xv = 0.5f * (base[(size_t)(2 * tau) * 2048] + base[(size_t)(2 * tau + 1) * 2048]);
        } else {
            xv = 0.25f * (base[(size_t)(4 * tau) * 2048] + base[(size_t)(4 * tau + 1) * 2048]
                        + base[(size_t)(4 * tau + 2) * 2048] + base[(size_t)(4 * tau + 3) * 2048]);
        }
        acc = fmaf(cw[(s * 1024 + c) * 4 + k], xv, acc);
    }
    xc[idx] = siluf_(acc);
}

// ---------------------------------------------------------------------------
// Chunked selective scan — R10 control flow (CHUNK=32, fold-in-pass2),
// j-split across 2 block groups of 8 states. 896 blocks per pass.
// State layout: [s][b][chunk][j][d] (d fastest), j in [0,16).
// soff: s0=0, s1=1048576, s2=1572864 (units of 1024-float j-rows... same as R10).
// ---------------------------------------------------------------------------
__device__ __forceinline__ void scan_decode(int blk, int& s, int& nchunk, int& Ts,
                                            int& dquad, int& chunk, int& b, size_t& soff)
{
    int local;
    if (blk < 256)      { s = 0; local = blk;       soff = 0; }
    else if (blk < 384) { s = 1; local = blk - 256; soff = 1048576; }
    else                { s = 2; local = blk - 384; soff = 1572864; }
    nchunk = 32 >> s;
    Ts = 1024 >> s;
    dquad = local & 3;
    chunk = (local >> 2) & (nchunk - 1);
    b = local >> (7 - s);
}

__global__ __launch_bounds__(256) void scan_pass1(
    const float* __restrict__ dt0, const float* __restrict__ xc0, const float* __restrict__ pj0,
    const float* __restrict__ dt1, const float* __restrict__ xc1, const float* __restrict__ pj1,
    const float* __restrict__ dt2, const float* __restrict__ xc2, const float* __restrict__ pj2,
    const float* __restrict__ A_log,
    float* __restrict__ prodA_buf, float* __restrict__ h_buf)
{
    const int jhalf = (blockIdx.x >= 448) ? 1 : 0;
    const int jo = jhalf * 8;
    int s, nchunk, Ts, dquad, chunk, b; size_t soff;
    scan_decode(blockIdx.x - jhalf * 448, s, nchunk, Ts, dquad, chunk, b, soff);
    const float* dt = (s == 0) ? dt0 : (s == 1) ? dt1 : dt2;
    const float* xc = (s == 0) ? xc0 : (s == 1) ? xc1 : xc2;
    const float* pj = (s == 0) ? pj0 : (s == 1) ? pj1 : pj2;

    const int d = dquad * 256 + threadIdx.x;
    const size_t rowbase = (size_t)b * Ts;
    const int t0 = chunk * CHUNK;

    float Acoef[8], h[8], p[8];
#pragma unroll
    for (int j = 0; j < 8; j++) {
        Acoef[j] = -__expf(A_log[((size_t)(s * DINNER + d)) * 16 + jo + j]);
        h[j] = 0.f; p[j] = 1.f;
    }

    __shared__ float bcB[CHUNK][8];
    if (threadIdx.x < CHUNK * 8) {
        int i = threadIdx.x >> 3, jj = threadIdx.x & 7;
        bcB[i][jj] = pj[(rowbase + t0 + i) * 96 + 64 + jo + jj];
    }
    __syncthreads();

    for (int i = 0; i < CHUNK; i++) {
        size_t t = rowbase + t0 + i;
        float dtv = dt[t * DINNER + d];
        float xv  = xc[t * DINNER + d];
#pragma unroll
        for (int j = 0; j < 8; j++) {
            float dA  = fmaxf(__expf(dtv * Acoef[j]), 1e-38f);
            float dbx = fmaxf(dtv * bcB[i][j] * xv, 1e-38f);
            h[j] = fmaf(dA, h[j], dbx);
            p[j] *= dA;
        }
    }

    size_t base = soff + (size_t)((b * nchunk + chunk) * 16 + jo) * 1024 + d;
#pragma unroll
    for (int j = 0; j < 8; j++) {
        prodA_buf[base + (size_t)j * 1024] = p[j];
        h_buf[base + (size_t)j * 1024] = h[j];
    }
}

__global__ __launch_bounds__(256) void scan_pass2(
    const float* __restrict__ dt0, const float* __restrict__ xc0,
    const float* __restrict__ pj0,
    const float* __restrict__ dt1, const float* __restrict__ xc1,
    const float* __restrict__ pj1,
    const float* __restrict__ dt2, const float* __restrict__ xc2,
    const float* __restrict__ pj2,
    float* __restrict__ ya0, float* __restrict__ ya1, float* __restrict__ ya2,
    float* __restrict__ yb0, float* __restrict__ yb1, float* __restrict__ yb2,
    const float* __restrict__ A_log, const float* __restrict__ D_p,
    const float* __restrict__ prodA_buf, const float* __restrict__ h_buf)
{
    const int jhalf = (blockIdx.x >= 448) ? 1 : 0;
    const int jo = jhalf * 8;
    int s, nchunk, Ts, dquad, chunk, b; size_t soff;
    scan_decode(blockIdx.x - jhalf * 448, s, nchunk, Ts, dquad, chunk, b, soff);
    const float* dt = (s == 0) ? dt0 : (s == 1) ? dt1 : dt2;
    const float* xc = (s == 0) ? xc0 : (s == 1) ? xc1 : xc2;
    const float* pj = (s == 0) ? pj0 : (s == 1) ? pj1 : pj2;
    float* y = jhalf ? ((s == 0) ? yb0 : (s == 1) ? yb1 : yb2)
                     : ((s == 0) ? ya0 : (s == 1) ? ya1 : ya2);

    const int d = dquad * 256 + threadIdx.x;
    const size_t rowbase = (size_t)b * Ts;
    const int t0 = chunk * CHUNK;

    float Acoef[8], h[8];
#pragma unroll
    for (int j = 0; j < 8; j++) {
        Acoef[j] = -__expf(A_log[((size_t)(s * DINNER + d)) * 16 + jo + j]);
        h[j] = 0.f;
    }
    const float Dp = (jhalf == 0) ? D_p[s * DINNER + d] : 0.f;

    // carry-in: fold predecessor chunk states for our 8 j's (read-only)
    for (int c = 0; c < chunk; c++) {
        size_t cb = soff + (size_t)((b * nchunk + c) * 16 + jo) * 1024 + d;
#pragma unroll
        for (int j = 0; j < 8; j++)
            h[j] = fmaf(prodA_buf[cb + (size_t)j * 1024], h[j], h_buf[cb + (size_t)j * 1024]);
    }

    __shared__ float bc[CHUNK][16];   // B (0..7) and C (8..15) for our 8 j's
    for (int u = threadIdx.x; u < CHUNK * 16; u += 256) {
        int i = u >> 4, jj = u & 15;
        int col = (jj < 8) ? (64 + jo + jj) : (80 + jo + (jj - 8));
        bc[i][jj] = pj[(rowbase + t0 + i) * 96 + col];
    }
    __syncthreads();

    for (int i = 0; i < CHUNK; i++) {
        size_t t = rowbase + t0 + i;
        float dtv = dt[t * DINNER + d];
        float xv  = xc[t * DINNER + d];
        float accy = 0.f;
#pragma unroll
        for (int j = 0; j < 8; j++) {
            float dA  = fmaxf(__expf(dtv * Acoef[j]), 1e-38f);
            float dbx = fmaxf(dtv * bc[i][j] * xv, 1e-38f);
            h[j] = fmaf(dA, h[j], dbx);
            accy = fmaf(bc[i][8 + j], h[j], accy);
        }
        y[t * DINNER + d] = accy + Dp * xv;
    }
}

// ---------------------------------------------------------------------------
__global__ __launch_bounds__(256) void ln_kernel(
    const float* __restrict__ yin, const float* __restrict__ gamma,
    const float* __restrict__ beta, float* __restrict__ out)
{
    int token = blockIdx.x;
    int tid = threadIdx.x;
    const float* row = yin + (size_t)token * DIMSZ;
    float v0 = row[tid], v1 = row[tid + 256];
    __shared__ float s1[256], s2[256];
    s1[tid] = v0 + v1;
    s2[tid] = v0 * v0 + v1 * v1;
    __syncthreads();
    for (int off = 128; off > 0; off >>= 1) {
        if (tid < off) { s1[tid] += s1[tid + off]; s2[tid] += s2[tid + off]; }
        __syncthreads();
    }
    float mu = s1[0] * (1.f / 512.f);
    float var = s2[0] * (1.f / 512.f) - mu * mu;
    float rstd = rsqrtf(var + 1e-5f);
    float* orow = out + (size_t)token * DIMSZ;
    orow[tid]       = (v0 - mu) * rstd * gamma[tid]       + beta[tid];
    orow[tid + 256] = (v1 - mu) * rstd * gamma[tid + 256] + beta[tid + 256];
}

// ---------------------------------------------------------------------------
extern "C" void kernel_launch(void* const* d_in, const int* in_sizes, int n_in,
                              void* d_out, int out_size, void* d_ws, size_t ws_size,
                              hipStream_t stream)
{
    const float* x         = (const float*)d_in[0];
    const float* in_proj_w = (const float*)d_in[1];
    const float* conv_w    = (const float*)d_in[2];
    const float* conv_b    = (const float*)d_in[3];
    const float* xproj_w   = (const float*)d_in[4];
    const float* dtproj_w  = (const float*)d_in[5];
    const float* dtproj_b  = (const float*)d_in[6];
    const float* A_log     = (const float*)d_in[7];
    const float* D_p       = (const float*)d_in[8];
    const float* scale_w   = (const float*)d_in[9];
    const float* cg_w1     = (const float*)d_in[10];
    const float* cg_w2     = (const float*)d_in[11];
    const float* out_pw    = (const float*)d_in[12];
    const float* ln_gamma  = (const float*)d_in[13];
    const float* ln_beta   = (const float*)d_in[14];
    float* out = (float*)d_out;

    float* ws = (float*)d_ws;
    // f32 workspace layout (element offsets)
    float* xz    = ws;                       // 4,194,304  (2048 x 2048)
    float* xc0   = xz    + 4194304;          // xc stacked 3584x1024
    float* xc1   = xc0   + 2097152;
    float* xc2   = xc1   + 1048576;
    float* pj0   = xc2   + 524288;           // pj stacked 3584x96
    float* pj1   = pj0   + 196608;
    float* pj2   = pj1   + 98304;
    float* dt0   = pj2   + 49152;            // dt stacked 3584x1024
    float* dt1   = dt0   + 2097152;
    float* dt2   = dt1   + 1048576;
    float* ya0   = dt2   + 524288;           // y partial A (j<8)
    float* ya1   = ya0   + 2097152;
    float* ya2   = ya1   + 1048576;
    float* yb0   = ya2   + 524288;           // y partial B (j>=8)
    float* yb1   = yb0   + 2097152;
    float* yb2   = yb1   + 1048576;
    float* prodA = yb2   + 524288;           // 1,835,008 (CHUNK=32 states)
    float* hbuf  = prodA + 1835008;          // 1,835,008
    // total: 23,887,872 floats = 95.6 MB

    // Overlays (lifetime-checked):
    float* h1     = dt1;   // cg1 out (2048x512); dt dead after pass2
    float* fusedg = dt0;   // cg2 out (2048x1024); y stays live for cg2
    float* outpre = xc1;   // out_proj out; xc dead after pass2

    // P1) in_proj: xz = x @ in_proj_w^T  (M=2048,N=2048,K=512) — 1024 blocks
    mgemm_kernel<0, false, false, false, false><<<dim3(32, 32), 256, 0, stream>>>(
        x, DIMSZ, DIMSZ, in_proj_w, nullptr, nullptr, nullptr,
        nullptr, nullptr, nullptr, nullptr, nullptr, nullptr, nullptr, xz, 2048);

    // P2) fused downsample+conv+SiLU — 14336 blocks
    conv_fused_kernel<<<14336, 256, 0, stream>>>(xz, conv_w, conv_b, xc0);

    // P3) xproj stacked MFMA (M=3584,N=96,K=1024) — 112 blocks
    xproj_mfma_kernel<<<dim3(56, 2), 256, 0, stream>>>(xc0, xproj_w, pj0);

    // P4) dtproj stacked (M=3584,N=1024,K=64, A=pj cols 0..63) — 896 blocks
    mgemm_kernel<3, false, true, false, false><<<dim3(56, 16), 256, 0, stream>>>(
        pj0, 96, DTRANK, dtproj_w, dtproj_b, nullptr, nullptr,
        nullptr, nullptr, nullptr, nullptr, nullptr, nullptr, nullptr, dt0, 1024);

    // P5/P6) chunked selective scan, j-split — 896 blocks each
    scan_pass1<<<896, 256, 0, stream>>>(dt0, xc0, pj0, dt1, xc1, pj1,
                                        dt2, xc2, pj2, A_log, prodA, hbuf);
    scan_pass2<<<896, 256, 0, stream>>>(dt0, xc0, pj0, dt1, xc1, pj1,
                                        dt2, xc2, pj2,
                                        ya0, ya1, ya2, yb0, yb1, yb2,
                                        A_log, D_p, prodA, hbuf);

    // P7) cg1 (ctx on-the-fly from yA+yB): h1 = silu(ctx @ cg_w1^T)
    //     (N=512,K=1024) — 256 blocks
    mgemm_kernel<1, false, false, true, false><<<dim3(32, 8), 256, 0, stream>>>(
        nullptr, DINNER, DINNER, cg_w1, nullptr, nullptr, nullptr,
        ya0, ya1, ya2, yb0, yb1, yb2, nullptr, h1, 512);

    // P8) cg2 + softmax-fuse + gate: fusedg = fused(yA+yB,sw) * sigmoid(h1@cg_w2^T) * silu(gate)
    //     (N=1024,K=512) — 512 blocks
    mgemm_kernel<2, false, false, false, true><<<dim3(32, 16), 256, 0, stream>>>(
        h1, 512, 512, cg_w2, nullptr, nullptr, xz,
        ya0, ya1, ya2, yb0, yb1, yb2, scale_w, fusedg, 1024);

    // P9) out_proj + residual: outpre = fusedg @ out_pw^T + x (N=512,K=1024)
    mgemm_kernel<0, true, false, false, false><<<dim3(32, 8), 256, 0, stream>>>(
        fusedg, DINNER, DINNER, out_pw, nullptr, x, nullptr,
        nullptr, nullptr, nullptr, nullptr, nullptr, nullptr, nullptr, outpre, 512);

    // P10) LayerNorm
    ln_kernel<<<BATCH * SEQ, 256, 0, stream>>>(outpre, ln_gamma, ln_beta, out);
}

// Round 13
// 281.746 us; speedup vs baseline: 1.0564x; 1.0516x over previous
//
#include <hip/hip_runtime.h>
#include <hip/hip_bf16.h>

// HierarchicalMambaBlock: B=2,T=1024,DIM=512 -> D_INNER=1024, DT_RANK=64, D_STATE=16
// All tensors f32. GEMMs on MFMA via ON-THE-FLY split precision:
// stage f32 tiles into LDS as hi/lo bf16; acc += Ah*Bh + Al*Bh + Ah*Bl (~f32 accurate).
// Scan: CHUNK=32, fold-in-pass2, j-dimension split across 2 block groups (8 states
// each, 896 blocks/pass); partials recombined by a small combine_y kernel.
#define BATCH   2
#define SEQ     1024
#define DIMSZ   512
#define DINNER  1024
#define DTRANK  64
#define DSTATE  16
#define CHUNK   32

typedef __hip_bfloat16 bf16;
typedef __attribute__((ext_vector_type(8))) short s8v;   // 8 bf16 MFMA frag
typedef __attribute__((ext_vector_type(4))) float f4v;   // 4 f32 acc

__device__ __forceinline__ float sigmoidf_(float x) { return 1.f / (1.f + __expf(-x)); }
__device__ __forceinline__ float siluf_(float x) { return x * sigmoidf_(x); }
__device__ __forceinline__ void split2(float v, bf16& hi, bf16& lo) {
    hi = __float2bfloat16(v);
    lo = __float2bfloat16(v - __bfloat162float(hi));
}
__device__ __forceinline__ void split_store4(const float4 v,
                                             bf16* __restrict__ ph,
                                             bf16* __restrict__ pl) {
    union { bf16 b[4]; uint2 u; } H, L;
    split2(v.x, H.b[0], L.b[0]); split2(v.y, H.b[1], L.b[1]);
    split2(v.z, H.b[2], L.b[2]); split2(v.w, H.b[3], L.b[3]);
    *reinterpret_cast<uint2*>(ph) = H.u;
    *reinterpret_cast<uint2*>(pl) = L.u;
}

// ---------------------------------------------------------------------------
// MFMA GEMM, 64x64 tile, BK=64 f32, 4 waves (each 32x32 of 16x16x32 frags),
// register prefetch of next K-tile. A,W f32; split to hi/lo at LDS stage.
// ACT: 0 none, 1 silu, 2 sigmoid, 3 bias+softplus
// DT_MODE: stacked dtproj (M=3584): per-block W/bias select by scale
// CTX_A:   A[m,k] = (y0[m,k] + y1[up(m),k] + y2[up(m),k]) / 3   (cg1 fusion)
// GATE3:   v = softmax_fused(y0,y1,y2,sw)[gm,gn] * v * silu(xz gate)  (cg2 fusion)
// Requires: M,N multiples of 64, K multiple of 64, lda%4==0.
// ---------------------------------------------------------------------------
template <int ACT, bool ADD_RES, bool DT_MODE, bool CTX_A, bool GATE3>
__global__ __launch_bounds__(256) void mgemm_kernel(
    const float* __restrict__ A, int lda, int K,
    const float* __restrict__ W,            // ldw = K
    const float* __restrict__ bias,
    const float* __restrict__ res,          // residual (ADD_RES)
    const float* __restrict__ gxz,          // xz (GATE3)
    const float* __restrict__ yy0,          // CTX_A / GATE3 (combined y per scale)
    const float* __restrict__ yy1,
    const float* __restrict__ yy2,
    const float* __restrict__ swp,          // GATE3 softmax weights (3)
    float* __restrict__ C, int N)
{
    __shared__ bf16 Ah[64][72], Al[64][72], Bh[64][72], Bl[64][72];

    const int m0 = blockIdx.x * 64;
    const int n0 = blockIdx.y * 64;
    const int tid = threadIdx.x;
    const int wave = tid >> 6;
    const int lane = tid & 63;
    const int wm = (wave >> 1) * 32;
    const int wn = (wave & 1) * 32;
    const int m16 = lane & 15;
    const int q   = lane >> 4;

    int scale = 0;
    if (DT_MODE) scale = (m0 < 2048) ? 0 : ((m0 < 3072) ? 1 : 2);
    const float* Wp = DT_MODE ? (W + (size_t)scale * 1024 * K) : W;
    const float* bias_p = (ACT == 3) ? (DT_MODE ? bias + (size_t)scale * N : bias) : nullptr;

    f4v acc[2][2];
#pragma unroll
    for (int i = 0; i < 2; i++)
#pragma unroll
        for (int j = 0; j < 2; j++)
#pragma unroll
            for (int r = 0; r < 4; r++) acc[i][j][r] = 0.f;

    const int cch = tid & 15;
    const int c4  = cch * 4;
    const int r0  = tid >> 4;

    // A row pointers (CTX_A: three upsample-indexed sources)
    const float* a0p[4]; const float* a1p[4]; const float* a2p[4];
#pragma unroll
    for (int p = 0; p < 4; p++) {
        int m = m0 + r0 + p * 16;
        if (CTX_A) {
            int b = m >> 10, t = m & 1023;
            a0p[p] = yy0 + (size_t)m * 1024 + c4;
            a1p[p] = yy1 + (size_t)((b << 9) + (t >> 1)) * 1024 + c4;
            a2p[p] = yy2 + (size_t)((b << 8) + (t >> 2)) * 1024 + c4;
        } else {
            a0p[p] = A + (size_t)m * lda + c4;
        }
    }
    const float* Bbase = Wp + (size_t)(n0 + r0) * K + c4;

    const int nkt = K >> 6;
    float4 ra[4], rb[4];
#pragma unroll
    for (int p = 0; p < 4; p++) {
        if (CTX_A) {
            float4 u = *reinterpret_cast<const float4*>(a0p[p]);
            float4 v = *reinterpret_cast<const float4*>(a1p[p]);
            float4 w = *reinterpret_cast<const float4*>(a2p[p]);
            ra[p] = make_float4((u.x + v.x + w.x) * (1.f / 3.f), (u.y + v.y + w.y) * (1.f / 3.f),
                                (u.z + v.z + w.z) * (1.f / 3.f), (u.w + v.w + w.w) * (1.f / 3.f));
        } else {
            ra[p] = *reinterpret_cast<const float4*>(a0p[p]);
        }
        rb[p] = *reinterpret_cast<const float4*>(Bbase + (size_t)(p * 16) * K);
    }

    for (int kt = 0; kt < nkt; kt++) {
        if (kt) __syncthreads();
#pragma unroll
        for (int p = 0; p < 4; p++) {
            int r = r0 + p * 16;
            split_store4(ra[p], &Ah[r][c4], &Al[r][c4]);
            split_store4(rb[p], &Bh[r][c4], &Bl[r][c4]);
        }
        __syncthreads();
        if (kt + 1 < nkt) {
            int off = (kt + 1) * 64;
#pragma unroll
            for (int p = 0; p < 4; p++) {
                if (CTX_A) {
                    float4 u = *reinterpret_cast<const float4*>(a0p[p] + off);
                    float4 v = *reinterpret_cast<const float4*>(a1p[p] + off);
                    float4 w = *reinterpret_cast<const float4*>(a2p[p] + off);
                    ra[p] = make_float4((u.x + v.x + w.x) * (1.f / 3.f), (u.y + v.y + w.y) * (1.f / 3.f),
                                        (u.z + v.z + w.z) * (1.f / 3.f), (u.w + v.w + w.w) * (1.f / 3.f));
                } else {
                    ra[p] = *reinterpret_cast<const float4*>(a0p[p] + off);
                }
                rb[p] = *reinterpret_cast<const float4*>(Bbase + off + (size_t)(p * 16) * K);
            }
        }
#pragma unroll
        for (int kk = 0; kk < 2; kk++) {
            const int col = kk * 32 + q * 8;
            s8v ah[2], al[2], bh[2], bl[2];
#pragma unroll
            for (int i = 0; i < 2; i++) {
                int ar = wm + i * 16 + m16;
                ah[i] = *reinterpret_cast<const s8v*>(&Ah[ar][col]);
                al[i] = *reinterpret_cast<const s8v*>(&Al[ar][col]);
                int br = wn + i * 16 + m16;
                bh[i] = *reinterpret_cast<const s8v*>(&Bh[br][col]);
                bl[i] = *reinterpret_cast<const s8v*>(&Bl[br][col]);
            }
#pragma unroll
            for (int i = 0; i < 2; i++)
#pragma unroll
                for (int j = 0; j < 2; j++) {
                    acc[i][j] = __builtin_amdgcn_mfma_f32_16x16x32_bf16(ah[i], bh[j], acc[i][j], 0, 0, 0);
                    acc[i][j] = __builtin_amdgcn_mfma_f32_16x16x32_bf16(al[i], bh[j], acc[i][j], 0, 0, 0);
                    acc[i][j] = __builtin_amdgcn_mfma_f32_16x16x32_bf16(ah[i], bl[j], acc[i][j], 0, 0, 0);
                }
        }
    }

    // GATE3 softmax weights
    float e0 = 0.f, e1 = 0.f, e2 = 0.f, inv = 0.f;
    if (GATE3) {
        float s0 = swp[0], s1 = swp[1], s2 = swp[2];
        float mx = fmaxf(s0, fmaxf(s1, s2));
        e0 = __expf(s0 - mx); e1 = __expf(s1 - mx); e2 = __expf(s2 - mx);
        inv = 1.f / (e0 + e1 + e2);
    }

    // Epilogue. D mapping (verified): row = q*4 + reg, col = lane&15.
#pragma unroll
    for (int i = 0; i < 2; i++) {
#pragma unroll
        for (int j = 0; j < 2; j++) {
#pragma unroll
            for (int r = 0; r < 4; r++) {
                int gm = m0 + wm + i * 16 + q * 4 + r;
                int gn = n0 + wn + j * 16 + m16;
                float v = acc[i][j][r];
                if (ACT == 3) { v += bias_p[gn]; v = (v > 20.f) ? v : __logf(1.f + __expf(v)); }
                else if (ACT == 1) v = siluf_(v);
                else if (ACT == 2) v = sigmoidf_(v);
                if (GATE3) {
                    int b = gm >> 10, t = gm & 1023;
                    float f = (e0 * yy0[(size_t)gm * 1024 + gn]
                             + e1 * yy1[(size_t)((b << 9) + (t >> 1)) * 1024 + gn]
                             + e2 * yy2[(size_t)((b << 8) + (t >> 2)) * 1024 + gn]) * inv;
                    v = f * v * siluf_(gxz[(size_t)gm * 2048 + 1024 + gn]);
                } else if (ADD_RES) {
                    v += res[(size_t)gm * N + gn];
                }
                C[(size_t)gm * N + gn] = v;
            }
        }
    }
}

// ---------------------------------------------------------------------------
// xproj MFMA: stacked M=3584, N=96 (clamped), K=1024, ldc=96. Grid (56,2).
// ---------------------------------------------------------------------------
__global__ __launch_bounds__(256) void xproj_mfma_kernel(
    const float* __restrict__ A, const float* __restrict__ xw,
    float* __restrict__ pj)
{
    const int K = 1024;
    __shared__ bf16 Ah[64][72], Al[64][72], Bh[64][72], Bl[64][72];

    const int m0 = blockIdx.x * 64;
    const int n0 = blockIdx.y * 64;
    const int tid = threadIdx.x;
    const int wave = tid >> 6;
    const int lane = tid & 63;
    const int wm = (wave >> 1) * 32;
    const int wn = (wave & 1) * 32;
    const int m16 = lane & 15;
    const int q   = lane >> 4;

    const int scale = (m0 < 2048) ? 0 : ((m0 < 3072) ? 1 : 2);
    const float* Wp = xw + (size_t)scale * 96 * K;

    f4v acc[2][2];
#pragma unroll
    for (int i = 0; i < 2; i++)
#pragma unroll
        for (int j = 0; j < 2; j++)
#pragma unroll
            for (int r = 0; r < 4; r++) acc[i][j][r] = 0.f;

    const int cch = tid & 15;
    const int c4  = cch * 4;
    const int r0  = tid >> 4;

    const float* Abase = A + (size_t)(m0 + r0) * K + c4;
    const float* Bbase = Wp + (size_t)(n0 + r0) * K + c4;
    bool bok[4];
#pragma unroll
    for (int p = 0; p < 4; p++) bok[p] = (n0 + r0 + p * 16) < 96;

    const int nkt = K >> 6;
    float4 ra[4], rb[4];
    const float4 zero4 = make_float4(0.f, 0.f, 0.f, 0.f);
#pragma unroll
    for (int p = 0; p < 4; p++) {
        ra[p] = *reinterpret_cast<const float4*>(Abase + (size_t)(p * 16) * K);
        rb[p] = bok[p] ? *reinterpret_cast<const float4*>(Bbase + (size_t)(p * 16) * K) : zero4;
    }

    for (int kt = 0; kt < nkt; kt++) {
        if (kt) __syncthreads();
#pragma unroll
        for (int p = 0; p < 4; p++) {
            int r = r0 + p * 16;
            split_store4(ra[p], &Ah[r][c4], &Al[r][c4]);
            split_store4(rb[p], &Bh[r][c4], &Bl[r][c4]);
        }
        __syncthreads();
        if (kt + 1 < nkt) {
            int off = (kt + 1) * 64;
#pragma unroll
            for (int p = 0; p < 4; p++) {
                ra[p] = *reinterpret_cast<const float4*>(Abase + off + (size_t)(p * 16) * K);
                rb[p] = bok[p] ? *reinterpret_cast<const float4*>(Bbase + off + (size_t)(p * 16) * K) : zero4;
            }
        }
#pragma unroll
        for (int kk = 0; kk < 2; kk++) {
            const int col = kk * 32 + q * 8;
            s8v ah[2], al[2], bh[2], bl[2];
#pragma unroll
            for (int i = 0; i < 2; i++) {
                int ar = wm + i * 16 + m16;
                ah[i] = *reinterpret_cast<const s8v*>(&Ah[ar][col]);
                al[i] = *reinterpret_cast<const s8v*>(&Al[ar][col]);
                int br = wn + i * 16 + m16;
                bh[i] = *reinterpret_cast<const s8v*>(&Bh[br][col]);
                bl[i] = *reinterpret_cast<const s8v*>(&Bl[br][col]);
            }
#pragma unroll
            for (int i = 0; i < 2; i++)
#pragma unroll
                for (int j = 0; j < 2; j++) {
                    acc[i][j] = __builtin_amdgcn_mfma_f32_16x16x32_bf16(ah[i], bh[j], acc[i][j], 0, 0, 0);
                    acc[i][j] = __builtin_amdgcn_mfma_f32_16x16x32_bf16(al[i], bh[j], acc[i][j], 0, 0, 0);
                    acc[i][j] = __builtin_amdgcn_mfma_f32_16x16x32_bf16(ah[i], bl[j], acc[i][j], 0, 0, 0);
                }
        }
    }

#pragma unroll
    for (int i = 0; i < 2; i++) {
#pragma unroll
        for (int j = 0; j < 2; j++) {
            int gn = n0 + wn + j * 16 + m16;
            if (gn >= 96) continue;
#pragma unroll
            for (int r = 0; r < 4; r++) {
                int gm = m0 + wm + i * 16 + q * 4 + r;
                pj[(size_t)gm * 96 + gn] = acc[i][j][r];
            }
        }
    }
}

// ---------------------------------------------------------------------------
// Fused downsample + depthwise causal conv(K=4) + bias + SiLU, all 3 scales.
// ---------------------------------------------------------------------------
__global__ void conv_fused_kernel(const float* __restrict__ xz,
                                  const float* __restrict__ cw,
                                  const float* __restrict__ cb,
                                  float* __restrict__ xc)
{
    int idx = blockIdx.x * blockDim.x + threadIdx.x;
    if (idx >= 3670016) return;
    int s, rel;
    if (idx < 2097152)      { s = 0; rel = idx; }
    else if (idx < 3145728) { s = 1; rel = idx - 2097152; }
    else                    { s = 2; rel = idx - 3145728; }
    int c = rel & 1023;
    int row = rel >> 10;
    int Ts = 1024 >> s;
    int b = row / Ts;
    int t = row - b * Ts;
    const float* base = xz + (size_t)(b * 1024) * 2048 + c;

    float acc = cb[s * 1024 + c];
#pragma unroll
    for (int k = 0; k < 4; k++) {
        int tau = t - 3 + k;
        if (tau < 0) continue;
        float xv;
        if (s == 0) {
            xv = base[(size_t)tau * 2048];
        } else if (s == 1) {
            xv = 0.5f * (base[(size_t)(2 * tau) * 2048] + base[(size_t)(2 * tau + 1) * 2048]);
        } else {
            xv = 0.25f * (base[(size_t)(4 * tau) * 2048] + base[(size_t)(4 * tau + 1) * 2048]
                        + base[(size_t)(4 * tau + 2) * 2048] + base[(size_t)(4 * tau + 3) * 2048]);
        }
        acc = fmaf(cw[(s * 1024 + c) * 4 + k], xv, acc);
    }
    xc[idx] = siluf_(acc);
}

// ---------------------------------------------------------------------------
// Chunked selective scan — CHUNK=32, fold-in-pass2, j-split (8 states/block).
// 896 blocks per pass. State layout: [s][b][chunk][j][d] (d fastest).
// ---------------------------------------------------------------------------
__device__ __forceinline__ void scan_decode(int blk, int& s, int& nchunk, int& Ts,
                                            int& dquad, int& chunk, int& b, size_t& soff)
{
    int local;
    if (blk < 256)      { s = 0; local = blk;       soff = 0; }
    else if (blk < 384) { s = 1; local = blk - 256; soff = 1048576; }
    else                { s = 2; local = blk - 384; soff = 1572864; }
    nchunk = 32 >> s;
    Ts = 1024 >> s;
    dquad = local & 3;
    chunk = (local >> 2) & (nchunk - 1);
    b = local >> (7 - s);
}

__global__ __launch_bounds__(256) void scan_pass1(
    const float* __restrict__ dt0, const float* __restrict__ xc0, const float* __restrict__ pj0,
    const float* __restrict__ dt1, const float* __restrict__ xc1, const float* __restrict__ pj1,
    const float* __restrict__ dt2, const float* __restrict__ xc2, const float* __restrict__ pj2,
    const float* __restrict__ A_log,
    float* __restrict__ prodA_buf, float* __restrict__ h_buf)
{
    const int jhalf = (blockIdx.x >= 448) ? 1 : 0;
    const int jo = jhalf * 8;
    int s, nchunk, Ts, dquad, chunk, b; size_t soff;
    scan_decode(blockIdx.x - jhalf * 448, s, nchunk, Ts, dquad, chunk, b, soff);
    const float* dt = (s == 0) ? dt0 : (s == 1) ? dt1 : dt2;
    const float* xc = (s == 0) ? xc0 : (s == 1) ? xc1 : xc2;
    const float* pj = (s == 0) ? pj0 : (s == 1) ? pj1 : pj2;

    const int d = dquad * 256 + threadIdx.x;
    const size_t rowbase = (size_t)b * Ts;
    const int t0 = chunk * CHUNK;

    float Acoef[8], h[8], p[8];
#pragma unroll
    for (int j = 0; j < 8; j++) {
        Acoef[j] = -__expf(A_log[((size_t)(s * DINNER + d)) * 16 + jo + j]);
        h[j] = 0.f; p[j] = 1.f;
    }

    __shared__ float bcB[CHUNK][8];
    if (threadIdx.x < CHUNK * 8) {
        int i = threadIdx.x >> 3, jj = threadIdx.x & 7;
        bcB[i][jj] = pj[(rowbase + t0 + i) * 96 + 64 + jo + jj];
    }
    __syncthreads();

    for (int i = 0; i < CHUNK; i++) {
        size_t t = rowbase + t0 + i;
        float dtv = dt[t * DINNER + d];
        float xv  = xc[t * DINNER + d];
#pragma unroll
        for (int j = 0; j < 8; j++) {
            float dA  = fmaxf(__expf(dtv * Acoef[j]), 1e-38f);
            float dbx = fmaxf(dtv * bcB[i][j] * xv, 1e-38f);
            h[j] = fmaf(dA, h[j], dbx);
            p[j] *= dA;
        }
    }

    size_t base = soff + (size_t)((b * nchunk + chunk) * 16 + jo) * 1024 + d;
#pragma unroll
    for (int j = 0; j < 8; j++) {
        prodA_buf[base + (size_t)j * 1024] = p[j];
        h_buf[base + (size_t)j * 1024] = h[j];
    }
}

__global__ __launch_bounds__(256) void scan_pass2(
    const float* __restrict__ dt0, const float* __restrict__ xc0,
    const float* __restrict__ pj0,
    const float* __restrict__ dt1, const float* __restrict__ xc1,
    const float* __restrict__ pj1,
    const float* __restrict__ dt2, const float* __restrict__ xc2,
    const float* __restrict__ pj2,
    float* __restrict__ ya0, float* __restrict__ ya1, float* __restrict__ ya2,
    float* __restrict__ yb0, float* __restrict__ yb1, float* __restrict__ yb2,
    const float* __restrict__ A_log, const float* __restrict__ D_p,
    const float* __restrict__ prodA_buf, const float* __restrict__ h_buf)
{
    const int jhalf = (blockIdx.x >= 448) ? 1 : 0;
    const int jo = jhalf * 8;
    int s, nchunk, Ts, dquad, chunk, b; size_t soff;
    scan_decode(blockIdx.x - jhalf * 448, s, nchunk, Ts, dquad, chunk, b, soff);
    const float* dt = (s == 0) ? dt0 : (s == 1) ? dt1 : dt2;
    const float* xc = (s == 0) ? xc0 : (s == 1) ? xc1 : xc2;
    const float* pj = (s == 0) ? pj0 : (s == 1) ? pj1 : pj2;
    float* y = jhalf ? ((s == 0) ? yb0 : (s == 1) ? yb1 : yb2)
                     : ((s == 0) ? ya0 : (s == 1) ? ya1 : ya2);

    const int d = dquad * 256 + threadIdx.x;
    const size_t rowbase = (size_t)b * Ts;
    const int t0 = chunk * CHUNK;

    float Acoef[8], h[8];
#pragma unroll
    for (int j = 0; j < 8; j++) {
        Acoef[j] = -__expf(A_log[((size_t)(s * DINNER + d)) * 16 + jo + j]);
        h[j] = 0.f;
    }
    const float Dp = (jhalf == 0) ? D_p[s * DINNER + d] : 0.f;

    // carry-in: fold predecessor chunk states for our 8 j's (read-only)
    for (int c = 0; c < chunk; c++) {
        size_t cb = soff + (size_t)((b * nchunk + c) * 16 + jo) * 1024 + d;
#pragma unroll
        for (int j = 0; j < 8; j++)
            h[j] = fmaf(prodA_buf[cb + (size_t)j * 1024], h[j], h_buf[cb + (size_t)j * 1024]);
    }

    __shared__ float bc[CHUNK][16];   // B (0..7) and C (8..15) for our 8 j's
    for (int u = threadIdx.x; u < CHUNK * 16; u += 256) {
        int i = u >> 4, jj = u & 15;
        int col = (jj < 8) ? (64 + jo + jj) : (80 + jo + (jj - 8));
        bc[i][jj] = pj[(rowbase + t0 + i) * 96 + col];
    }
    __syncthreads();

    for (int i = 0; i < CHUNK; i++) {
        size_t t = rowbase + t0 + i;
        float dtv = dt[t * DINNER + d];
        float xv  = xc[t * DINNER + d];
        float accy = 0.f;
#pragma unroll
        for (int j = 0; j < 8; j++) {
            float dA  = fmaxf(__expf(dtv * Acoef[j]), 1e-38f);
            float dbx = fmaxf(dtv * bc[i][j] * xv, 1e-38f);
            h[j] = fmaf(dA, h[j], dbx);
            accy = fmaf(bc[i][8 + j], h[j], accy);
        }
        y[t * DINNER + d] = accy + Dp * xv;
    }
}

// ---------------------------------------------------------------------------
// combine_y: ysum = yA + yB (contiguous 3,670,016 floats each, float4 vec).
// Write-once into the dead dt region; no RMW of any producer buffer.
// ---------------------------------------------------------------------------
__global__ void combine_y_kernel(const float* __restrict__ ya,
                                 const float* __restrict__ yb,
                                 float* __restrict__ ysum)
{
    int idx = blockIdx.x * blockDim.x + threadIdx.x;   // 917,504 float4s
    float4 a = reinterpret_cast<const float4*>(ya)[idx];
    float4 b = reinterpret_cast<const float4*>(yb)[idx];
    reinterpret_cast<float4*>(ysum)[idx] =
        make_float4(a.x + b.x, a.y + b.y, a.z + b.z, a.w + b.w);
}

// ---------------------------------------------------------------------------
__global__ __launch_bounds__(256) void ln_kernel(
    const float* __restrict__ yin, const float* __restrict__ gamma,
    const float* __restrict__ beta, float* __restrict__ out)
{
    int token = blockIdx.x;
    int tid = threadIdx.x;
    const float* row = yin + (size_t)token * DIMSZ;
    float v0 = row[tid], v1 = row[tid + 256];
    __shared__ float s1[256], s2[256];
    s1[tid] = v0 + v1;
    s2[tid] = v0 * v0 + v1 * v1;
    __syncthreads();
    for (int off = 128; off > 0; off >>= 1) {
        if (tid < off) { s1[tid] += s1[tid + off]; s2[tid] += s2[tid + off]; }
        __syncthreads();
    }
    float mu = s1[0] * (1.f / 512.f);
    float var = s2[0] * (1.f / 512.f) - mu * mu;
    float rstd = rsqrtf(var + 1e-5f);
    float* orow = out + (size_t)token * DIMSZ;
    orow[tid]       = (v0 - mu) * rstd * gamma[tid]       + beta[tid];
    orow[tid + 256] = (v1 - mu) * rstd * gamma[tid + 256] + beta[tid + 256];
}

// ---------------------------------------------------------------------------
extern "C" void kernel_launch(void* const* d_in, const int* in_sizes, int n_in,
                              void* d_out, int out_size, void* d_ws, size_t ws_size,
                              hipStream_t stream)
{
    const float* x         = (const float*)d_in[0];
    const float* in_proj_w = (const float*)d_in[1];
    const float* conv_w    = (const float*)d_in[2];
    const float* conv_b    = (const float*)d_in[3];
    const float* xproj_w   = (const float*)d_in[4];
    const float* dtproj_w  = (const float*)d_in[5];
    const float* dtproj_b  = (const float*)d_in[6];
    const float* A_log     = (const float*)d_in[7];
    const float* D_p       = (const float*)d_in[8];
    const float* scale_w   = (const float*)d_in[9];
    const float* cg_w1     = (const float*)d_in[10];
    const float* cg_w2     = (const float*)d_in[11];
    const float* out_pw    = (const float*)d_in[12];
    const float* ln_gamma  = (const float*)d_in[13];
    const float* ln_beta   = (const float*)d_in[14];
    float* out = (float*)d_out;

    float* ws = (float*)d_ws;
    // f32 workspace layout (element offsets)
    float* xz    = ws;                       // 4,194,304  (2048 x 2048)
    float* xc0   = xz    + 4194304;          // xc stacked 3584x1024
    float* xc1   = xc0   + 2097152;
    float* xc2   = xc1   + 1048576;
    float* pj0   = xc2   + 524288;           // pj stacked 3584x96
    float* pj1   = pj0   + 196608;
    float* pj2   = pj1   + 98304;
    float* dt0   = pj2   + 49152;            // dt stacked 3584x1024
    float* dt1   = dt0   + 2097152;
    float* dt2   = dt1   + 1048576;
    float* ya0   = dt2   + 524288;           // y partial A (j<8), contiguous
    float* ya1   = ya0   + 2097152;
    float* ya2   = ya1   + 1048576;
    float* yb0   = ya2   + 524288;           // y partial B (j>=8), contiguous
    float* yb1   = yb0   + 2097152;
    float* yb2   = yb1   + 1048576;
    float* prodA = yb2   + 524288;           // 1,835,008 (CHUNK=32 states)
    float* hbuf  = prodA + 1835008;          // 1,835,008
    // total: 23,887,872 floats = 95.6 MB

    // Overlays (lifetime-checked; all strictly produce-then-consume):
    float* ysum0  = dt0;                  // combined y (dt dead after pass2)
    float* ysum1  = dt0 + 2097152;
    float* ysum2  = dt0 + 3145728;
    float* fusedg = xc0;                  // cg2 out (xc dead after pass2)
    float* h1     = xc1;                  // cg1 out (within xc stack, dead)
    float* outpre = prodA;                // out_proj out (prodA dead after pass2)

    // P1) in_proj: xz = x @ in_proj_w^T  (M=2048,N=2048,K=512) — 1024 blocks
    mgemm_kernel<0, false, false, false, false><<<dim3(32, 32), 256, 0, stream>>>(
        x, DIMSZ, DIMSZ, in_proj_w, nullptr, nullptr, nullptr,
        nullptr, nullptr, nullptr, nullptr, xz, 2048);

    // P2) fused downsample+conv+SiLU — 14336 blocks
    conv_fused_kernel<<<14336, 256, 0, stream>>>(xz, conv_w, conv_b, xc0);

    // P3) xproj stacked MFMA (M=3584,N=96,K=1024) — 112 blocks
    xproj_mfma_kernel<<<dim3(56, 2), 256, 0, stream>>>(xc0, xproj_w, pj0);

    // P4) dtproj stacked (M=3584,N=1024,K=64, A=pj cols 0..63) — 896 blocks
    mgemm_kernel<3, false, true, false, false><<<dim3(56, 16), 256, 0, stream>>>(
        pj0, 96, DTRANK, dtproj_w, dtproj_b, nullptr, nullptr,
        nullptr, nullptr, nullptr, nullptr, dt0, 1024);

    // P5/P6) chunked selective scan, j-split — 896 blocks each
    scan_pass1<<<896, 256, 0, stream>>>(dt0, xc0, pj0, dt1, xc1, pj1,
                                        dt2, xc2, pj2, A_log, prodA, hbuf);
    scan_pass2<<<896, 256, 0, stream>>>(dt0, xc0, pj0, dt1, xc1, pj1,
                                        dt2, xc2, pj2,
                                        ya0, ya1, ya2, yb0, yb1, yb2,
                                        A_log, D_p, prodA, hbuf);

    // P7) combine partials: ysum = yA + yB — 3584 blocks (float4)
    combine_y_kernel<<<3584, 256, 0, stream>>>(ya0, yb0, ysum0);

    // P8) cg1 (ctx on-the-fly from ysum): h1 = silu(ctx @ cg_w1^T)
    //     (N=512,K=1024) — 256 blocks
    mgemm_kernel<1, false, false, true, false><<<dim3(32, 8), 256, 0, stream>>>(
        nullptr, DINNER, DINNER, cg_w1, nullptr, nullptr, nullptr,
        ysum0, ysum1, ysum2, nullptr, h1, 512);

    // P9) cg2 + softmax-fuse + gate: fusedg = fused(ysum,sw) * sigmoid(h1@cg_w2^T) * silu(gate)
    //     (N=1024,K=512) — 512 blocks
    mgemm_kernel<2, false, false, false, true><<<dim3(32, 16), 256, 0, stream>>>(
        h1, 512, 512, cg_w2, nullptr, nullptr, xz,
        ysum0, ysum1, ysum2, scale_w, fusedg, 1024);

    // P10) out_proj + residual: outpre = fusedg @ out_pw^T + x (N=512,K=1024)
    mgemm_kernel<0, true, false, false, false><<<dim3(32, 8), 256, 0, stream>>>(
        fusedg, DINNER, DINNER, out_pw, nullptr, x, nullptr,
        nullptr, nullptr, nullptr, nullptr, outpre, 512);

    // P11) LayerNorm
    ln_kernel<<<BATCH * SEQ, 256, 0, stream>>>(outpre, ln_gamma, ln_beta, out);
}